// Round 4
// baseline (220.802 us; speedup 1.0000x reference)
//
#include <hip/hip_runtime.h>

typedef unsigned int uint;

#define B_ 2
#define C_ 128
#define H_ 96
#define W_ 96
#define HEADS_ 4
#define HD_ 32
#define M_ 16
#define WIN_ 7
#define PAD_ 3
#define N_ (H_*W_)              // 9216
#define HP_ (H_+2*PAD_)         // 102
#define KW_ (WIN_*WIN_)         // 49
#define TILE_ 8                 // attn tile is 8x8 pixels
#define HALO_ (TILE_+WIN_-1)    // 14
#define NHALO_ (HALO_*HALO_)    // 196
#define CU_ (C_/2)              // channels as packed bf16 pairs (uints) = 64

static __device__ __forceinline__ uint f2bf(float f) {
    uint u = __float_as_uint(f);
    u = (u + 0x7fffu + ((u >> 16) & 1u)) >> 16;   // RNE to bf16
    return u & 0xffffu;
}
static __device__ __forceinline__ uint pack2(float a, float b) {
    return f2bf(a) | (f2bf(b) << 16);
}
static __device__ __forceinline__ float bf_lo(uint u){ return __uint_as_float(u << 16); }
static __device__ __forceinline__ float bf_hi(uint u){ return __uint_as_float(u & 0xffff0000u); }

// inline function, not a macro: macro params named w/x/y/z collide with
// float4 member access under preprocessor substitution.
static __device__ __forceinline__ void fma4(float4& acc, float s, const float4& v) {
    acc.x = fmaf(s, v.x, acc.x);
    acc.y = fmaf(s, v.y, acc.y);
    acc.z = fmaf(s, v.z, acc.z);
    acc.w = fmaf(s, v.w, acc.w);
}

// ---------------------------------------------------------------------------
// Kernel 1: fill padded borders of Kp/Vp (bf16-packed) with bias (= proj of
// zero input), and build phiT: [B][102][102][16] fp32, border = 1.0
// ---------------------------------------------------------------------------
__global__ __launch_bounds__(256) void pad_fill(
    const float* __restrict__ phi, const float* __restrict__ bk, const float* __restrict__ bv,
    uint* __restrict__ Kp, uint* __restrict__ Vp, float* __restrict__ PhiT)
{
    int idx = blockIdx.x * 256 + threadIdx.x;
    const int tot = B_*HP_*HP_;
    if (idx >= tot) return;
    int b  = idx / (HP_*HP_);
    int pp = idx % (HP_*HP_);
    int py = pp / HP_, px = pp % HP_;
    bool interior = (py >= PAD_ && py < H_+PAD_ && px >= PAD_ && px < W_+PAD_);
    if (!interior) {
        size_t base = ((size_t)b*HP_*HP_ + pp) * CU_;
        #pragma unroll 4
        for (int c8 = 0; c8 < 16; ++c8) {   // 16 x uint4 = 64 uints = 128 bf16
            const float4 ka = ((const float4*)bk)[c8*2];
            const float4 kb = ((const float4*)bk)[c8*2+1];
            const float4 va = ((const float4*)bv)[c8*2];
            const float4 vb = ((const float4*)bv)[c8*2+1];
            uint4 ku, vu;
            ku.x = pack2(ka.x, ka.y); ku.y = pack2(ka.z, ka.w);
            ku.z = pack2(kb.x, kb.y); ku.w = pack2(kb.z, kb.w);
            vu.x = pack2(va.x, va.y); vu.y = pack2(va.z, va.w);
            vu.z = pack2(vb.x, vb.y); vu.w = pack2(vb.z, vb.w);
            ((uint4*)(Kp + base))[c8] = ku;
            ((uint4*)(Vp + base))[c8] = vu;
        }
    }
    size_t pb = ((size_t)b*HP_*HP_ + pp) * M_;
    if (interior) {
        int y = py - PAD_, xx = px - PAD_;
        #pragma unroll
        for (int m = 0; m < M_; ++m)
            PhiT[pb + m] = phi[((size_t)b*M_ + m)*N_ + y*W_ + xx];
    } else {
        #pragma unroll
        for (int m = 0; m < M_; ++m) PhiT[pb + m] = 1.0f;
    }
}

// ---------------------------------------------------------------------------
// Kernel 2: fused Q/K/V projection (fp32 GEMV tiles).
// Q written fp32 [B][N][C]; K/V written bf16-packed into padded layout.
// ---------------------------------------------------------------------------
__global__ __launch_bounds__(256, 3) void qkv_proj(
    const float* __restrict__ x,
    const float* __restrict__ Wq, const float* __restrict__ bq,
    const float* __restrict__ Wk, const float* __restrict__ bk,
    const float* __restrict__ Wv, const float* __restrict__ bv,
    float* __restrict__ Qp, uint* __restrict__ Kp, uint* __restrict__ Vp)
{
    __shared__ float4 ldsW4[64*32];   // 64 ci rows x 128 co  (32 KB)
    __shared__ float4 ldsX4[128*8];   // [ci][pix] 128 x 32   (16 KB)

    const int t   = threadIdx.x;
    const int blk = blockIdx.x;                 // B_*(N_/32) = 576
    const int b   = blk / (N_/32);
    const int n0  = (blk % (N_/32)) * 32;

    for (int idx = t; idx < 128*32; idx += 256) {
        int pix = idx & 31, ci = idx >> 5;
        ((float*)ldsX4)[ci*32 + pix] = x[((size_t)b*C_ + ci)*N_ + n0 + pix];
    }

    const float* Ws[3] = {Wq, Wk, Wv};
    const float* bs[3] = {bq, bk, bv};

    const int co_g  = t & 31;   // co = co_g*4 .. +3
    const int pix_g = t >> 5;   // pix = pix_g*4 .. +3

    for (int pj = 0; pj < 3; ++pj) {
        float4 bias = *(const float4*)(bs[pj] + co_g*4);
        float4 acc0 = bias, acc1 = bias, acc2 = bias, acc3 = bias;
        for (int half = 0; half < 2; ++half) {
            __syncthreads();
            const float4* wsrc = (const float4*)(Ws[pj] + (size_t)half*64*C_);
            for (int idx = t; idx < 64*32; idx += 256) ldsW4[idx] = wsrc[idx];
            __syncthreads();
            #pragma unroll 8
            for (int ci = 0; ci < 64; ++ci) {
                float4 xv = ldsX4[(half*64 + ci)*8 + pix_g];
                float4 wv = ldsW4[ci*32 + co_g];
                fma4(acc0, xv.x, wv);
                fma4(acc1, xv.y, wv);
                fma4(acc2, xv.z, wv);
                fma4(acc3, xv.w, wv);
            }
        }
        float4 accs[4] = {acc0, acc1, acc2, acc3};
        #pragma unroll
        for (int p = 0; p < 4; ++p) {
            int n = n0 + pix_g*4 + p;
            if (pj == 0) {
                *(float4*)(Qp + ((size_t)b*N_ + n)*C_ + co_g*4) = accs[p];
            } else {
                int y = n / W_, xx = n % W_;
                size_t rowb = ((size_t)b*HP_ + (y+PAD_))*HP_ + (xx+PAD_);
                uint* dst = (pj == 1) ? Kp : Vp;
                uint2 u;
                u.x = pack2(accs[p].x, accs[p].y);
                u.y = pack2(accs[p].z, accs[p].w);
                *(uint2*)(dst + rowb*CU_ + co_g*2) = u;
            }
        }
    }
}

// ---------------------------------------------------------------------------
// Kernel 3: local attention, 4 threads per (pixel, head).
// Block = (b, head, 8x8 tile); 256 threads = 64 pixels x 4 sub-lanes.
// Sub-lane s owns channels [s*8,s*8+8) and phi dims [s*4,s*4+4).
// Logits distributed: lane s stores exp-weights for kk === s (mod 4) -> 13
// regs, no spill. Butterfly-transpose reduce yields logit 4j+s on lane s.
// PV pass broadcasts weights with width-4 shfl.
// XCD swizzle: tile = (bx&7)*18 + bx>>3 so each XCD owns a contiguous image
// strip (~3.2MB working set < 4MB L2).
// ---------------------------------------------------------------------------
__global__ __launch_bounds__(256, 4) void attn(
    const float* __restrict__ Qp, const uint* __restrict__ Kp, const uint* __restrict__ Vp,
    const float* __restrict__ PhiT, const float* __restrict__ log_alpha,
    const float* __restrict__ beta, float* __restrict__ AO)
{
    __shared__ uint4  kl[NHALO_*4];   // 196 rows x 4 slots (8 bf16) = 12544 B
    __shared__ uint4  vl[NHALO_*4];   // 12544 B
    __shared__ float4 pl[NHALO_*4];   // 196 rows x 16 fp32 phi     = 12544 B

    const int t  = threadIdx.x;
    const int h  = blockIdx.y;
    const int b  = blockIdx.z;
    const int bx = blockIdx.x;
    const int tile = ((bx & 7) * 18) + (bx >> 3);   // 144 = 8*18, bijective
    const int y0 = (tile / (W_/TILE_)) * TILE_;
    const int x0 = (tile % (W_/TILE_)) * TILE_;

    // stage halo: K/V bf16 copy, phi fp32
    for (int idx = t; idx < NHALO_*4; idx += 256) {
        int hp = idx >> 2, sb = idx & 3;
        int hy = hp / HALO_, hx = hp % HALO_;
        size_t rowb = (((size_t)b*HP_ + (y0+hy))*HP_ + (x0+hx));
        kl[idx] = *(const uint4*)(Kp + rowb*CU_ + h*16 + sb*4);
        vl[idx] = *(const uint4*)(Vp + rowb*CU_ + h*16 + sb*4);
        pl[idx] = *(const float4*)(PhiT + rowb*M_ + sb*4);
    }
    __syncthreads();

    const int s  = t & 3;       // sub-lane: channels s*8.., phi dims s*4..
    const int p  = t >> 2;      // pixel 0..63
    const int qy = p >> 3, qx = p & 7;
    const int n  = (y0+qy)*W_ + (x0+qx);
    const bool c1 = (s & 1) != 0;
    const bool c2 = (s & 2) != 0;

    float4 q0, q1;
    {
        const float* qptr = Qp + ((size_t)b*N_ + n)*C_ + h*HD_ + s*8;
        q0 = ((const float4*)qptr)[0];
        q1 = ((const float4*)qptr)[1];
    }
    float4 pc = pl[((qy+PAD_)*HALO_ + (qx+PAD_))*4 + s];

    const float alpha = __expf(log_alpha[0]);
    const float scale = 0.17677669529663687f;                 // HD^-0.5 = 1/sqrt(32)
    const float gcoef = -beta[h] * alpha * 0.17677669529663687f; // -beta*alpha/sqrt(2M)

    // per-lane partial of logit at window pos hp (lane's 8 ch + 4 phi dims)
    auto partial = [&](int hp) -> float {
        uint4 kw = kl[(hp<<2) + s];
        float4 acc = make_float4(0.f,0.f,0.f,0.f);
        acc.x = fmaf(q0.x, bf_lo(kw.x), acc.x);
        acc.y = fmaf(q0.y, bf_hi(kw.x), acc.y);
        acc.z = fmaf(q0.z, bf_lo(kw.y), acc.z);
        acc.w = fmaf(q0.w, bf_hi(kw.y), acc.w);
        acc.x = fmaf(q1.x, bf_lo(kw.z), acc.x);
        acc.y = fmaf(q1.y, bf_hi(kw.z), acc.y);
        acc.z = fmaf(q1.z, bf_lo(kw.w), acc.z);
        acc.w = fmaf(q1.w, bf_hi(kw.w), acc.w);
        float pdot = (acc.x + acc.y) + (acc.z + acc.w);
        float4 pv = pl[(hp<<2) + s];
        float d0 = pc.x - pv.x, d1 = pc.y - pv.y;
        float d2 = pc.z - pv.z, d3 = pc.w - pv.w;
        float pdsq = fmaf(d0,d0, fmaf(d1,d1, fmaf(d2,d2, d3*d3)));
        return fmaf(pdot, scale, gcoef*pdsq);
    };

    float lp[13];
    // groups of 4 logits: butterfly-transpose so lane s gets logit 4g+s
    #pragma unroll
    for (int g = 0; g < 12; ++g) {
        float pr0, pr1, pr2, pr3;
        {
            int kk = g*4;
            pr0 = partial((qy + (kk  )/WIN_)*HALO_ + qx + (kk  )%WIN_);
            pr1 = partial((qy + (kk+1)/WIN_)*HALO_ + qx + (kk+1)%WIN_);
            pr2 = partial((qy + (kk+2)/WIN_)*HALO_ + qx + (kk+2)%WIN_);
            pr3 = partial((qy + (kk+3)/WIN_)*HALO_ + qx + (kk+3)%WIN_);
        }
        float Av = (c1 ? pr1 : pr0) + __shfl_xor(c1 ? pr0 : pr1, 1);
        float Bv = (c1 ? pr3 : pr2) + __shfl_xor(c1 ? pr2 : pr3, 1);
        lp[g] = (c2 ? Bv : Av) + __shfl_xor(c2 ? Av : Bv, 2);
    }
    {   // kk = 48: plain butterfly, all lanes hold it; only lane 0's is "owned"
        float pr = partial((qy+6)*HALO_ + (qx+6));
        pr += __shfl_xor(pr, 1);
        pr += __shfl_xor(pr, 2);
        lp[12] = pr;
    }

    // softmax over distributed logits
    float mx = lp[0];
    #pragma unroll
    for (int g = 1; g < 13; ++g) mx = fmaxf(mx, lp[g]);
    mx = fmaxf(mx, __shfl_xor(mx, 1));
    mx = fmaxf(mx, __shfl_xor(mx, 2));

    float ssum = 0.f;
    #pragma unroll
    for (int g = 0; g < 12; ++g) { float e = __expf(lp[g]-mx); lp[g] = e; ssum += e; }
    {
        float e = (s == 0) ? __expf(lp[12]-mx) : 0.f;
        lp[12] = e; ssum += e;
    }
    ssum += __shfl_xor(ssum, 1);
    ssum += __shfl_xor(ssum, 2);
    float inv = 1.0f / ssum;

    // PV: broadcast weight for kk from lane kk&3 within the quad
    float4 o0 = make_float4(0.f,0.f,0.f,0.f);
    float4 o1 = make_float4(0.f,0.f,0.f,0.f);
    #pragma unroll
    for (int kk = 0; kk < KW_; ++kk) {
        int hp = (qy + kk/WIN_)*HALO_ + qx + kk%WIN_;
        float w = __shfl(lp[kk>>2], kk&3, 4);
        uint4 vw = vl[(hp<<2) + s];
        o0.x = fmaf(w, bf_lo(vw.x), o0.x);
        o0.y = fmaf(w, bf_hi(vw.x), o0.y);
        o0.z = fmaf(w, bf_lo(vw.y), o0.z);
        o0.w = fmaf(w, bf_hi(vw.y), o0.w);
        o1.x = fmaf(w, bf_lo(vw.z), o1.x);
        o1.y = fmaf(w, bf_hi(vw.z), o1.y);
        o1.z = fmaf(w, bf_lo(vw.w), o1.z);
        o1.w = fmaf(w, bf_hi(vw.w), o1.w);
    }
    float* aop = AO + ((size_t)b*N_ + n)*C_ + h*HD_ + s*8;
    o0.x *= inv; o0.y *= inv; o0.z *= inv; o0.w *= inv;
    o1.x *= inv; o1.y *= inv; o1.z *= inv; o1.w *= inv;
    ((float4*)aop)[0] = o0;
    ((float4*)aop)[1] = o1;
}

// ---------------------------------------------------------------------------
// Kernel 4: output projection.
// ---------------------------------------------------------------------------
__global__ __launch_bounds__(256, 4) void out_proj(
    const float* __restrict__ AO, const float* __restrict__ Wo,
    const float* __restrict__ bo, float* __restrict__ out)
{
    __shared__ float4 aos[64*32];   // 32 KB
    const int t   = threadIdx.x;
    const int blk = blockIdx.x;                 // B_*(N_/64) = 288
    const int b   = blk / (N_/64);
    const int n0  = (blk % (N_/64)) * 64;

    for (int idx = t; idx < 64*32; idx += 256) {
        int nl = idx >> 5, c4 = idx & 31;
        aos[nl*32 + (c4 ^ (nl & 31))] =
            ((const float4*)(AO + ((size_t)b*N_ + n0 + nl)*C_))[c4];
    }
    __syncthreads();

    const int nl = t & 63, cg = t >> 6;
    const int n  = n0 + nl;
    #pragma unroll
    for (int c8 = 0; c8 < 8; ++c8) {
        int co = cg*32 + c8*4;
        float4 acc = *(const float4*)(bo + co);
        #pragma unroll 8
        for (int c4 = 0; c4 < 32; ++c4) {
            float4 xv = aos[nl*32 + (c4 ^ (nl & 31))];
            float4 w0 = *(const float4*)(Wo + (size_t)(c4*4+0)*C_ + co);
            float4 w1 = *(const float4*)(Wo + (size_t)(c4*4+1)*C_ + co);
            float4 w2 = *(const float4*)(Wo + (size_t)(c4*4+2)*C_ + co);
            float4 w3 = *(const float4*)(Wo + (size_t)(c4*4+3)*C_ + co);
            fma4(acc, xv.x, w0);
            fma4(acc, xv.y, w1);
            fma4(acc, xv.z, w2);
            fma4(acc, xv.w, w3);
        }
        out[((size_t)b*C_ + co+0)*N_ + n] = acc.x;
        out[((size_t)b*C_ + co+1)*N_ + n] = acc.y;
        out[((size_t)b*C_ + co+2)*N_ + n] = acc.z;
        out[((size_t)b*C_ + co+3)*N_ + n] = acc.w;
    }
}

// ---------------------------------------------------------------------------
extern "C" void kernel_launch(void* const* d_in, const int* in_sizes, int n_in,
                              void* d_out, int out_size, void* d_ws, size_t ws_size,
                              hipStream_t stream)
{
    const float* x    = (const float*)d_in[0];
    const float* phi  = (const float*)d_in[1];
    const float* Wq   = (const float*)d_in[2];
    const float* bq   = (const float*)d_in[3];
    const float* Wk   = (const float*)d_in[4];
    const float* bk   = (const float*)d_in[5];
    const float* Wv   = (const float*)d_in[6];
    const float* bv   = (const float*)d_in[7];
    const float* Wo   = (const float*)d_in[8];
    const float* bo   = (const float*)d_in[9];
    const float* la   = (const float*)d_in[10];
    const float* beta = (const float*)d_in[11];
    float* out = (float*)d_out;

    // workspace layout. AO aliases Qp: each attn thread reads exactly the q
    // slice it later writes as AO (same n, same head, same channels).
    float* ws   = (float*)d_ws;
    float* Qp   = ws;                                   // B*N*C fp32      = 2,359,296 f
    uint*  Kp   = (uint*)(Qp + (size_t)B_*N_*C_);       // B*102^2*64 u32  = 1,331,712 u
    uint*  Vp   = Kp + (size_t)B_*HP_*HP_*CU_;          // 1,331,712 u
    float* PhiT = (float*)(Vp + (size_t)B_*HP_*HP_*CU_);// B*102^2*16 f    =   332,928 f
    float* AO   = Qp;                                   // aliased

    pad_fill<<<dim3((B_*HP_*HP_ + 255)/256), dim3(256), 0, stream>>>(phi, bk, bv, Kp, Vp, PhiT);
    qkv_proj<<<dim3(B_*(N_/32)), dim3(256), 0, stream>>>(x, Wq, bq, Wk, bk, Wv, bv, Qp, Kp, Vp);
    attn<<<dim3((H_/TILE_)*(W_/TILE_), HEADS_, B_), dim3(256), 0, stream>>>(Qp, Kp, Vp, PhiT, la, beta, AO);
    out_proj<<<dim3(B_*(N_/64)), dim3(256), 0, stream>>>(AO, Wo, bo, out);
}

// Round 5
// 149.333 us; speedup vs baseline: 1.4786x; 1.4786x over previous
//
#include <hip/hip_runtime.h>

typedef unsigned int uint;

#define B_ 2
#define C_ 128
#define H_ 96
#define W_ 96
#define HEADS_ 4
#define HD_ 32
#define M_ 16
#define WIN_ 7
#define PAD_ 3
#define N_ (H_*W_)              // 9216
#define HP_ (H_+2*PAD_)         // 102
#define HP2_ (HP_*HP_)          // 10404
#define KW_ (WIN_*WIN_)         // 49
#define TILE_ 8                 // attn tile is 8x8 pixels
#define HALO_ (TILE_+WIN_-1)    // 14
#define NHALO_ (HALO_*HALO_)    // 196

static __device__ __forceinline__ uint f2bf(float f) {
    uint u = __float_as_uint(f);
    u = (u + 0x7fffu + ((u >> 16) & 1u)) >> 16;   // RNE to bf16
    return u & 0xffffu;
}
static __device__ __forceinline__ uint pack2(float a, float b) {
    return f2bf(a) | (f2bf(b) << 16);
}
static __device__ __forceinline__ float bf_lo(uint u){ return __uint_as_float(u << 16); }
static __device__ __forceinline__ float bf_hi(uint u){ return __uint_as_float(u & 0xffff0000u); }

// inline function, not a macro: macro params named w/x/y/z collide with
// float4 member access under preprocessor substitution.
static __device__ __forceinline__ void fma4(float4& acc, float s, const float4& v) {
    acc.x = fmaf(s, v.x, acc.x);
    acc.y = fmaf(s, v.y, acc.y);
    acc.z = fmaf(s, v.z, acc.z);
    acc.w = fmaf(s, v.w, acc.w);
}

// ---------------------------------------------------------------------------
// KVp layout (head-major, K/V interleaved, bf16 pairs):
//   KVp[((b*HEADS+h)*HP2 + row)*32 + u], u<16: K pair u, u>=16: V pair u-16.
// One (row, head) = 128B = exactly one cache line; attn consumes lines fully.
// ---------------------------------------------------------------------------

// Kernel 1: fill padded borders of KVp with bias (= proj of zero input), and
// build PhiT: [B][102][102][16] fp32, border = 1.0
__global__ __launch_bounds__(256) void pad_fill(
    const float* __restrict__ phi, const float* __restrict__ bk, const float* __restrict__ bv,
    uint* __restrict__ KVp, float* __restrict__ PhiT)
{
    int idx = blockIdx.x * 256 + threadIdx.x;
    if (idx >= B_*HP2_) return;
    int b  = idx / HP2_;
    int pp = idx % HP2_;
    int py = pp / HP_, px = pp % HP_;
    bool interior = (py >= PAD_ && py < H_+PAD_ && px >= PAD_ && px < W_+PAD_);
    if (!interior) {
        #pragma unroll
        for (int h = 0; h < HEADS_; ++h) {
            size_t base = ((size_t)(b*HEADS_+h)*HP2_ + pp) * 32;
            #pragma unroll
            for (int q4i = 0; q4i < 4; ++q4i) {
                const float* kb8 = bk + h*HD_ + q4i*8;
                const float* vb8 = bv + h*HD_ + q4i*8;
                uint4 ku, vu;
                ku.x = pack2(kb8[0],kb8[1]); ku.y = pack2(kb8[2],kb8[3]);
                ku.z = pack2(kb8[4],kb8[5]); ku.w = pack2(kb8[6],kb8[7]);
                vu.x = pack2(vb8[0],vb8[1]); vu.y = pack2(vb8[2],vb8[3]);
                vu.z = pack2(vb8[4],vb8[5]); vu.w = pack2(vb8[6],vb8[7]);
                ((uint4*)(KVp + base))[q4i]     = ku;
                ((uint4*)(KVp + base))[4 + q4i] = vu;
            }
        }
    }
    size_t pb = ((size_t)b*HP2_ + pp) * M_;
    if (interior) {
        int y = py - PAD_, xx = px - PAD_;
        #pragma unroll
        for (int m = 0; m < M_; ++m)
            PhiT[pb + m] = phi[((size_t)b*M_ + m)*N_ + y*W_ + xx];
    } else {
        #pragma unroll
        for (int m = 0; m < M_; ++m) PhiT[pb + m] = 1.0f;
    }
}

// ---------------------------------------------------------------------------
// Kernel 2: Q/K/V projection, one projection per block (grid.z = 0/1/2).
// 32 pixels/block; x tile (16KB) + W half (32KB) in LDS; 4co x 4pix per thread.
// ---------------------------------------------------------------------------
__global__ __launch_bounds__(256, 3) void qkv_proj(
    const float* __restrict__ x,
    const float* __restrict__ Wq, const float* __restrict__ bq,
    const float* __restrict__ Wk, const float* __restrict__ bk,
    const float* __restrict__ Wv, const float* __restrict__ bv,
    float* __restrict__ Qp, uint* __restrict__ KVp)
{
    __shared__ float4 ldsW4[64*32];   // 64 ci x 128 co (32 KB)
    __shared__ float4 ldsX4[128*8];   // [ci][pix] 128 x 32 (16 KB)

    const int t  = threadIdx.x;
    const int n0 = blockIdx.x * 32;
    const int b  = blockIdx.y;
    const int pj = blockIdx.z;
    const float* Wsrc = (pj == 0) ? Wq : (pj == 1) ? Wk : Wv;
    const float* bsrc = (pj == 0) ? bq : (pj == 1) ? bk : bv;

    for (int idx = t; idx < 128*32; idx += 256) {
        int pix = idx & 31, ci = idx >> 5;
        ((float*)ldsX4)[ci*32 + pix] = x[((size_t)b*C_ + ci)*N_ + n0 + pix];
    }

    const int co_g  = t & 31;   // co = co_g*4 .. +3
    const int pix_g = t >> 5;   // pix = pix_g*4 .. +3

    float4 bias = *(const float4*)(bsrc + co_g*4);
    float4 acc0 = bias, acc1 = bias, acc2 = bias, acc3 = bias;
    for (int half = 0; half < 2; ++half) {
        __syncthreads();   // guards x-stage (half 0) and ldsW readers (half 1)
        const float4* wsrc4 = (const float4*)(Wsrc + (size_t)half*64*C_);
        for (int idx = t; idx < 64*32; idx += 256) ldsW4[idx] = wsrc4[idx];
        __syncthreads();
        #pragma unroll 8
        for (int ci = 0; ci < 64; ++ci) {
            float4 xv = ldsX4[(half*64 + ci)*8 + pix_g];
            float4 wv = ldsW4[ci*32 + co_g];
            fma4(acc0, xv.x, wv);
            fma4(acc1, xv.y, wv);
            fma4(acc2, xv.z, wv);
            fma4(acc3, xv.w, wv);
        }
    }
    float4 accs[4] = {acc0, acc1, acc2, acc3};
    #pragma unroll
    for (int p = 0; p < 4; ++p) {
        int n = n0 + pix_g*4 + p;
        if (pj == 0) {
            *(float4*)(Qp + ((size_t)b*N_ + n)*C_ + co_g*4) = accs[p];
        } else {
            int y = n / W_, xx = n % W_;
            size_t rowb = (size_t)(y+PAD_)*HP_ + (xx+PAD_);
            int h = co_g >> 3;
            int u = ((pj == 1) ? 0 : 16) + (co_g & 7)*2;
            uint2 uu;
            uu.x = pack2(accs[p].x, accs[p].y);
            uu.y = pack2(accs[p].z, accs[p].w);
            *(uint2*)(KVp + ((size_t)(b*HEADS_+h)*HP2_ + rowb)*32 + u) = uu;
        }
    }
}

// ---------------------------------------------------------------------------
// Kernel 3: local attention, 4 threads per (pixel, head), fully macro-unrolled
// so lp[] is only ever indexed by literals (NO runtime indexing -> registers).
// ---------------------------------------------------------------------------
__global__ __launch_bounds__(256, 3) void attn(
    const float* __restrict__ Qp, const uint* __restrict__ KVp,
    const float* __restrict__ PhiT, const float* __restrict__ log_alpha,
    const float* __restrict__ beta, float* __restrict__ AO)
{
    __shared__ uint4  kl[NHALO_*4];   // 12544 B
    __shared__ uint4  vl[NHALO_*4];   // 12544 B
    __shared__ float4 pl[NHALO_*4];   // 12544 B

    const int t  = threadIdx.x;
    const int h  = blockIdx.y;
    const int b  = blockIdx.z;
    const int bx = blockIdx.x;
    const int tile = ((bx & 7) * 18) + (bx >> 3);   // 144 = 8*18, bijective
    const int y0 = (tile / (W_/TILE_)) * TILE_;
    const int x0 = (tile % (W_/TILE_)) * TILE_;

    // stage K/V halo: one full 128B line per (row, head)
    const uint* kvb = KVp + (size_t)(b*HEADS_+h)*HP2_*32;
    for (int idx = t; idx < NHALO_*8; idx += 256) {
        int hp = idx >> 3, u4 = idx & 7;
        int hy = hp / HALO_, hx = hp % HALO_;
        size_t rowb = (size_t)(y0+hy)*HP_ + (x0+hx);
        uint4 val = *(const uint4*)(kvb + rowb*32 + u4*4);
        if (u4 < 4) kl[hp*4 + u4] = val;
        else        vl[hp*4 + (u4-4)] = val;
    }
    // stage phi halo (fp32)
    const float* pbase = PhiT + (size_t)b*HP2_*M_;
    for (int idx = t; idx < NHALO_*4; idx += 256) {
        int hp = idx >> 2, sb = idx & 3;
        int hy = hp / HALO_, hx = hp % HALO_;
        size_t rowb = (size_t)(y0+hy)*HP_ + (x0+hx);
        pl[idx] = *(const float4*)(pbase + rowb*M_ + sb*4);
    }
    __syncthreads();

    const int s  = t & 3;       // sub-lane: channels s*8.., phi dims s*4..
    const int p  = t >> 2;      // pixel 0..63
    const int qy = p >> 3, qx = p & 7;
    const int n  = (y0+qy)*W_ + (x0+qx);
    const bool c1 = (s & 1) != 0;
    const bool c2 = (s & 2) != 0;

    float4 q0, q1;
    {
        const float* qptr = Qp + ((size_t)b*N_ + n)*C_ + h*HD_ + s*8;
        q0 = ((const float4*)qptr)[0];
        q1 = ((const float4*)qptr)[1];
    }
    float4 pc = pl[((qy+PAD_)*HALO_ + (qx+PAD_))*4 + s];

    const float alpha = __expf(log_alpha[0]);
    const float scale = 0.17677669529663687f;                 // HD^-0.5
    const float gcoef = -beta[h] * alpha * 0.17677669529663687f; // -beta*alpha/sqrt(2M)

    auto partial = [&](int hp) -> float {
        uint4 kw = kl[(hp<<2) + s];
        float4 acc = make_float4(0.f,0.f,0.f,0.f);
        acc.x = fmaf(q0.x, bf_lo(kw.x), acc.x);
        acc.y = fmaf(q0.y, bf_hi(kw.x), acc.y);
        acc.z = fmaf(q0.z, bf_lo(kw.y), acc.z);
        acc.w = fmaf(q0.w, bf_hi(kw.y), acc.w);
        acc.x = fmaf(q1.x, bf_lo(kw.z), acc.x);
        acc.y = fmaf(q1.y, bf_hi(kw.z), acc.y);
        acc.z = fmaf(q1.z, bf_lo(kw.w), acc.z);
        acc.w = fmaf(q1.w, bf_hi(kw.w), acc.w);
        float pdot = (acc.x + acc.y) + (acc.z + acc.w);
        float4 pv = pl[(hp<<2) + s];
        float d0 = pc.x - pv.x, d1 = pc.y - pv.y;
        float d2 = pc.z - pv.z, d3 = pc.w - pv.w;
        float pdsq = fmaf(d0,d0, fmaf(d1,d1, fmaf(d2,d2, d3*d3)));
        return fmaf(pdot, scale, gcoef*pdsq);
    };

    float lp[13];
    float mx = -1e30f;

#define HPOS(KK) ((qy + (KK)/WIN_)*HALO_ + qx + ((KK)%WIN_))
#define LGROUP(G) { \
    float pr0 = partial(HPOS(4*(G)  )); \
    float pr1 = partial(HPOS(4*(G)+1)); \
    float pr2 = partial(HPOS(4*(G)+2)); \
    float pr3 = partial(HPOS(4*(G)+3)); \
    float Av = (c1 ? pr1 : pr0) + __shfl_xor(c1 ? pr0 : pr1, 1); \
    float Bv = (c1 ? pr3 : pr2) + __shfl_xor(c1 ? pr2 : pr3, 1); \
    float lg = (c2 ? Bv : Av) + __shfl_xor(c2 ? Av : Bv, 2); \
    lp[(G)] = lg; mx = fmaxf(mx, lg); }

    LGROUP(0) LGROUP(1) LGROUP(2) LGROUP(3) LGROUP(4) LGROUP(5)
    LGROUP(6) LGROUP(7) LGROUP(8) LGROUP(9) LGROUP(10) LGROUP(11)
    {   // kk = 48: all lanes hold it; only lane s==0 "owns" it
        float pr = partial(HPOS(48));
        pr += __shfl_xor(pr, 1);
        pr += __shfl_xor(pr, 2);
        lp[12] = pr; mx = fmaxf(mx, pr);
    }
    mx = fmaxf(mx, __shfl_xor(mx, 1));
    mx = fmaxf(mx, __shfl_xor(mx, 2));

    float ssum = 0.f;
#define EXPG(G) { float e = __expf(lp[(G)] - mx); lp[(G)] = e; ssum += e; }
    EXPG(0) EXPG(1) EXPG(2) EXPG(3) EXPG(4) EXPG(5)
    EXPG(6) EXPG(7) EXPG(8) EXPG(9) EXPG(10) EXPG(11)
    {
        float e = (s == 0) ? __expf(lp[12] - mx) : 0.f;
        lp[12] = e; ssum += e;
    }
    ssum += __shfl_xor(ssum, 1);
    ssum += __shfl_xor(ssum, 2);
    float inv = 1.0f / ssum;

    float4 o0 = make_float4(0.f,0.f,0.f,0.f);
    float4 o1 = make_float4(0.f,0.f,0.f,0.f);
#define PVPOS(KK) { \
    float wgt = __shfl(lp[(KK)>>2], (KK)&3, 4); \
    uint4 vw = vl[(HPOS(KK)<<2) + s]; \
    o0.x = fmaf(wgt, bf_lo(vw.x), o0.x); \
    o0.y = fmaf(wgt, bf_hi(vw.x), o0.y); \
    o0.z = fmaf(wgt, bf_lo(vw.y), o0.z); \
    o0.w = fmaf(wgt, bf_hi(vw.y), o0.w); \
    o1.x = fmaf(wgt, bf_lo(vw.z), o1.x); \
    o1.y = fmaf(wgt, bf_hi(vw.z), o1.y); \
    o1.z = fmaf(wgt, bf_lo(vw.w), o1.z); \
    o1.w = fmaf(wgt, bf_hi(vw.w), o1.w); }

    PVPOS(0)  PVPOS(1)  PVPOS(2)  PVPOS(3)  PVPOS(4)  PVPOS(5)  PVPOS(6)
    PVPOS(7)  PVPOS(8)  PVPOS(9)  PVPOS(10) PVPOS(11) PVPOS(12) PVPOS(13)
    PVPOS(14) PVPOS(15) PVPOS(16) PVPOS(17) PVPOS(18) PVPOS(19) PVPOS(20)
    PVPOS(21) PVPOS(22) PVPOS(23) PVPOS(24) PVPOS(25) PVPOS(26) PVPOS(27)
    PVPOS(28) PVPOS(29) PVPOS(30) PVPOS(31) PVPOS(32) PVPOS(33) PVPOS(34)
    PVPOS(35) PVPOS(36) PVPOS(37) PVPOS(38) PVPOS(39) PVPOS(40) PVPOS(41)
    PVPOS(42) PVPOS(43) PVPOS(44) PVPOS(45) PVPOS(46) PVPOS(47) PVPOS(48)

    float* aop = AO + ((size_t)b*N_ + n)*C_ + h*HD_ + s*8;
    o0.x *= inv; o0.y *= inv; o0.z *= inv; o0.w *= inv;
    o1.x *= inv; o1.y *= inv; o1.z *= inv; o1.w *= inv;
    ((float4*)aop)[0] = o0;
    ((float4*)aop)[1] = o1;
}

// ---------------------------------------------------------------------------
// Kernel 4: output projection.
// ---------------------------------------------------------------------------
__global__ __launch_bounds__(256, 4) void out_proj(
    const float* __restrict__ AO, const float* __restrict__ Wo,
    const float* __restrict__ bo, float* __restrict__ out)
{
    __shared__ float4 aos[64*32];   // 32 KB
    const int t   = threadIdx.x;
    const int blk = blockIdx.x;                 // B_*(N_/64) = 288
    const int b   = blk / (N_/64);
    const int n0  = (blk % (N_/64)) * 64;

    for (int idx = t; idx < 64*32; idx += 256) {
        int nl = idx >> 5, c4 = idx & 31;
        aos[nl*32 + (c4 ^ (nl & 31))] =
            ((const float4*)(AO + ((size_t)b*N_ + n0 + nl)*C_))[c4];
    }
    __syncthreads();

    const int nl = t & 63, cg = t >> 6;
    const int n  = n0 + nl;
    #pragma unroll
    for (int c8 = 0; c8 < 8; ++c8) {
        int co = cg*32 + c8*4;
        float4 acc = *(const float4*)(bo + co);
        #pragma unroll 8
        for (int c4 = 0; c4 < 32; ++c4) {
            float4 xv = aos[nl*32 + (c4 ^ (nl & 31))];
            float4 w0 = *(const float4*)(Wo + (size_t)(c4*4+0)*C_ + co);
            float4 w1 = *(const float4*)(Wo + (size_t)(c4*4+1)*C_ + co);
            float4 w2 = *(const float4*)(Wo + (size_t)(c4*4+2)*C_ + co);
            float4 w3 = *(const float4*)(Wo + (size_t)(c4*4+3)*C_ + co);
            fma4(acc, xv.x, w0);
            fma4(acc, xv.y, w1);
            fma4(acc, xv.z, w2);
            fma4(acc, xv.w, w3);
        }
        out[((size_t)b*C_ + co+0)*N_ + n] = acc.x;
        out[((size_t)b*C_ + co+1)*N_ + n] = acc.y;
        out[((size_t)b*C_ + co+2)*N_ + n] = acc.z;
        out[((size_t)b*C_ + co+3)*N_ + n] = acc.w;
    }
}

// ---------------------------------------------------------------------------
extern "C" void kernel_launch(void* const* d_in, const int* in_sizes, int n_in,
                              void* d_out, int out_size, void* d_ws, size_t ws_size,
                              hipStream_t stream)
{
    const float* x    = (const float*)d_in[0];
    const float* phi  = (const float*)d_in[1];
    const float* Wq   = (const float*)d_in[2];
    const float* bq   = (const float*)d_in[3];
    const float* Wk   = (const float*)d_in[4];
    const float* bk   = (const float*)d_in[5];
    const float* Wv   = (const float*)d_in[6];
    const float* bv   = (const float*)d_in[7];
    const float* Wo   = (const float*)d_in[8];
    const float* bo   = (const float*)d_in[9];
    const float* la   = (const float*)d_in[10];
    const float* beta = (const float*)d_in[11];
    float* out = (float*)d_out;

    // workspace layout. AO aliases Qp: each attn thread reads exactly the q
    // slice it later writes as AO (same n, same head, same channels).
    float* ws   = (float*)d_ws;
    float* Qp   = ws;                                        // 9.44 MB
    uint*  KVp  = (uint*)(Qp + (size_t)B_*N_*C_);            // 10.65 MB
    float* PhiT = (float*)(KVp + (size_t)B_*HEADS_*HP2_*32); // 1.33 MB
    float* AO   = Qp;                                        // aliased

    pad_fill<<<dim3((B_*HP2_ + 255)/256), dim3(256), 0, stream>>>(phi, bk, bv, KVp, PhiT);
    qkv_proj<<<dim3(N_/32, B_, 3), dim3(256), 0, stream>>>(x, Wq, bq, Wk, bk, Wv, bv, Qp, KVp);
    attn<<<dim3((H_/TILE_)*(W_/TILE_), HEADS_, B_), dim3(256), 0, stream>>>(Qp, KVp, PhiT, la, beta, AO);
    out_proj<<<dim3(B_*(N_/64)), dim3(256), 0, stream>>>(AO, Wo, bo, out);
}

// Round 6
// 95.930 us; speedup vs baseline: 2.3017x; 1.5567x over previous
//
#include <hip/hip_runtime.h>

typedef unsigned int uint;

#define B_ 2
#define C_ 128
#define H_ 96
#define W_ 96
#define HEADS_ 4
#define HD_ 32
#define M_ 16
#define WIN_ 7
#define PAD_ 3
#define N_ (H_*W_)              // 9216
#define HP_ (H_+2*PAD_)         // 102
#define HP2_ (HP_*HP_)          // 10404
#define KW_ (WIN_*WIN_)         // 49
#define TILE_ 8                 // attn tile is 8x8 pixels
#define HALO_ (TILE_+WIN_-1)    // 14
#define NHALO_ (HALO_*HALO_)    // 196

static __device__ __forceinline__ uint f2bf(float f) {
    uint u = __float_as_uint(f);
    u = (u + 0x7fffu + ((u >> 16) & 1u)) >> 16;   // RNE to bf16
    return u & 0xffffu;
}
static __device__ __forceinline__ uint pack2(float a, float b) {
    return f2bf(a) | (f2bf(b) << 16);
}
static __device__ __forceinline__ float bf_lo(uint u){ return __uint_as_float(u << 16); }
static __device__ __forceinline__ float bf_hi(uint u){ return __uint_as_float(u & 0xffff0000u); }

// inline function, not a macro: macro params named w/x/y/z collide with
// float4 member access under preprocessor substitution.
static __device__ __forceinline__ void fma4(float4& acc, float s, const float4& v) {
    acc.x = fmaf(s, v.x, acc.x);
    acc.y = fmaf(s, v.y, acc.y);
    acc.z = fmaf(s, v.z, acc.z);
    acc.w = fmaf(s, v.w, acc.w);
}

// ---------------------------------------------------------------------------
// KVp layout (head-major, K/V interleaved, bf16 pairs):
//   KVp[((b*HEADS+h)*HP2 + row)*32 + u], u<16: K pair u, u>=16: V pair u-16.
// One (row, head) = 128B = exactly one cache line; attn consumes lines fully.
// ---------------------------------------------------------------------------

// Kernel 1: fill padded borders of KVp with bias (= proj of zero input), and
// build PhiT: [B][102][102][16] fp32, border = 1.0
__global__ __launch_bounds__(256) void pad_fill(
    const float* __restrict__ phi, const float* __restrict__ bk, const float* __restrict__ bv,
    uint* __restrict__ KVp, float* __restrict__ PhiT)
{
    int idx = blockIdx.x * 256 + threadIdx.x;
    if (idx >= B_*HP2_) return;
    int b  = idx / HP2_;
    int pp = idx % HP2_;
    int py = pp / HP_, px = pp % HP_;
    bool interior = (py >= PAD_ && py < H_+PAD_ && px >= PAD_ && px < W_+PAD_);
    if (!interior) {
        #pragma unroll
        for (int h = 0; h < HEADS_; ++h) {
            size_t base = ((size_t)(b*HEADS_+h)*HP2_ + pp) * 32;
            #pragma unroll
            for (int q4i = 0; q4i < 4; ++q4i) {
                const float* kb8 = bk + h*HD_ + q4i*8;
                const float* vb8 = bv + h*HD_ + q4i*8;
                uint4 ku, vu;
                ku.x = pack2(kb8[0],kb8[1]); ku.y = pack2(kb8[2],kb8[3]);
                ku.z = pack2(kb8[4],kb8[5]); ku.w = pack2(kb8[6],kb8[7]);
                vu.x = pack2(vb8[0],vb8[1]); vu.y = pack2(vb8[2],vb8[3]);
                vu.z = pack2(vb8[4],vb8[5]); vu.w = pack2(vb8[6],vb8[7]);
                ((uint4*)(KVp + base))[q4i]     = ku;
                ((uint4*)(KVp + base))[4 + q4i] = vu;
            }
        }
    }
    size_t pb = ((size_t)b*HP2_ + pp) * M_;
    if (interior) {
        int y = py - PAD_, xx = px - PAD_;
        #pragma unroll
        for (int m = 0; m < M_; ++m)
            PhiT[pb + m] = phi[((size_t)b*M_ + m)*N_ + y*W_ + xx];
    } else {
        #pragma unroll
        for (int m = 0; m < M_; ++m) PhiT[pb + m] = 1.0f;
    }
}

// ---------------------------------------------------------------------------
// Kernel 2: Q/K/V projection, one projection per block (grid.z = 0/1/2).
// 32 pixels/block; x tile (16KB) + W half (32KB) in LDS; 4co x 4pix per thread.
// ---------------------------------------------------------------------------
__global__ __launch_bounds__(256, 3) void qkv_proj(
    const float* __restrict__ x,
    const float* __restrict__ Wq, const float* __restrict__ bq,
    const float* __restrict__ Wk, const float* __restrict__ bk,
    const float* __restrict__ Wv, const float* __restrict__ bv,
    float* __restrict__ Qp, uint* __restrict__ KVp)
{
    __shared__ float4 ldsW4[64*32];   // 64 ci x 128 co (32 KB)
    __shared__ float4 ldsX4[128*8];   // [ci][pix] 128 x 32 (16 KB)

    const int t  = threadIdx.x;
    const int n0 = blockIdx.x * 32;
    const int b  = blockIdx.y;
    const int pj = blockIdx.z;
    const float* Wsrc = (pj == 0) ? Wq : (pj == 1) ? Wk : Wv;
    const float* bsrc = (pj == 0) ? bq : (pj == 1) ? bk : bv;

    for (int idx = t; idx < 128*32; idx += 256) {
        int pix = idx & 31, ci = idx >> 5;
        ((float*)ldsX4)[ci*32 + pix] = x[((size_t)b*C_ + ci)*N_ + n0 + pix];
    }

    const int co_g  = t & 31;   // co = co_g*4 .. +3
    const int pix_g = t >> 5;   // pix = pix_g*4 .. +3

    float4 bias = *(const float4*)(bsrc + co_g*4);
    float4 acc0 = bias, acc1 = bias, acc2 = bias, acc3 = bias;
    for (int half = 0; half < 2; ++half) {
        __syncthreads();   // guards x-stage (half 0) and ldsW readers (half 1)
        const float4* wsrc4 = (const float4*)(Wsrc + (size_t)half*64*C_);
        for (int idx = t; idx < 64*32; idx += 256) ldsW4[idx] = wsrc4[idx];
        __syncthreads();
        #pragma unroll 8
        for (int ci = 0; ci < 64; ++ci) {
            float4 xv = ldsX4[(half*64 + ci)*8 + pix_g];
            float4 wv = ldsW4[ci*32 + co_g];
            fma4(acc0, xv.x, wv);
            fma4(acc1, xv.y, wv);
            fma4(acc2, xv.z, wv);
            fma4(acc3, xv.w, wv);
        }
    }
    float4 accs[4] = {acc0, acc1, acc2, acc3};
    #pragma unroll
    for (int p = 0; p < 4; ++p) {
        int n = n0 + pix_g*4 + p;
        if (pj == 0) {
            *(float4*)(Qp + ((size_t)b*N_ + n)*C_ + co_g*4) = accs[p];
        } else {
            int y = n / W_, xx = n % W_;
            size_t rowb = (size_t)(y+PAD_)*HP_ + (xx+PAD_);
            int h = co_g >> 3;
            int u = ((pj == 1) ? 0 : 16) + (co_g & 7)*2;
            uint2 uu;
            uu.x = pack2(accs[p].x, accs[p].y);
            uu.y = pack2(accs[p].z, accs[p].w);
            *(uint2*)(KVp + ((size_t)(b*HEADS_+h)*HP2_ + rowb)*32 + u) = uu;
        }
    }
}

// ---------------------------------------------------------------------------
// Kernel 3: local attention, 4 threads per (pixel, head), fully macro-unrolled
// so lp[] is only ever indexed by literals (NO runtime indexing -> registers).
// ---------------------------------------------------------------------------
__global__ __launch_bounds__(256, 3) void attn(
    const float* __restrict__ Qp, const uint* __restrict__ KVp,
    const float* __restrict__ PhiT, const float* __restrict__ log_alpha,
    const float* __restrict__ beta, float* __restrict__ AO)
{
    __shared__ uint4  kl[NHALO_*4];   // 12544 B
    __shared__ uint4  vl[NHALO_*4];   // 12544 B
    __shared__ float4 pl[NHALO_*4];   // 12544 B

    const int t  = threadIdx.x;
    const int h  = blockIdx.y;
    const int b  = blockIdx.z;
    const int bx = blockIdx.x;
    const int tile = ((bx & 7) * 18) + (bx >> 3);   // 144 = 8*18, bijective
    const int y0 = (tile / (W_/TILE_)) * TILE_;
    const int x0 = (tile % (W_/TILE_)) * TILE_;

    // stage K/V halo: one full 128B line per (row, head)
    const uint* kvb = KVp + (size_t)(b*HEADS_+h)*HP2_*32;
    for (int idx = t; idx < NHALO_*8; idx += 256) {
        int hp = idx >> 3, u4 = idx & 7;
        int hy = hp / HALO_, hx = hp % HALO_;
        size_t rowb = (size_t)(y0+hy)*HP_ + (x0+hx);
        uint4 val = *(const uint4*)(kvb + rowb*32 + u4*4);
        if (u4 < 4) kl[hp*4 + u4] = val;
        else        vl[hp*4 + (u4-4)] = val;
    }
    // stage phi halo (fp32)
    const float* pbase = PhiT + (size_t)b*HP2_*M_;
    for (int idx = t; idx < NHALO_*4; idx += 256) {
        int hp = idx >> 2, sb = idx & 3;
        int hy = hp / HALO_, hx = hp % HALO_;
        size_t rowb = (size_t)(y0+hy)*HP_ + (x0+hx);
        pl[idx] = *(const float4*)(pbase + rowb*M_ + sb*4);
    }
    __syncthreads();

    const int s  = t & 3;       // sub-lane: channels s*8.., phi dims s*4..
    const int p  = t >> 2;      // pixel 0..63
    const int qy = p >> 3, qx = p & 7;
    const int n  = (y0+qy)*W_ + (x0+qx);
    const bool c1 = (s & 1) != 0;
    const bool c2 = (s & 2) != 0;

    float4 q0, q1;
    {
        const float* qptr = Qp + ((size_t)b*N_ + n)*C_ + h*HD_ + s*8;
        q0 = ((const float4*)qptr)[0];
        q1 = ((const float4*)qptr)[1];
    }
    float4 pc = pl[((qy+PAD_)*HALO_ + (qx+PAD_))*4 + s];

    const float alpha = __expf(log_alpha[0]);
    const float scale = 0.17677669529663687f;                 // HD^-0.5
    const float gcoef = -beta[h] * alpha * 0.17677669529663687f; // -beta*alpha/sqrt(2M)

    auto partial = [&](int hp) -> float {
        uint4 kw = kl[(hp<<2) + s];
        float4 acc = make_float4(0.f,0.f,0.f,0.f);
        acc.x = fmaf(q0.x, bf_lo(kw.x), acc.x);
        acc.y = fmaf(q0.y, bf_hi(kw.x), acc.y);
        acc.z = fmaf(q0.z, bf_lo(kw.y), acc.z);
        acc.w = fmaf(q0.w, bf_hi(kw.y), acc.w);
        acc.x = fmaf(q1.x, bf_lo(kw.z), acc.x);
        acc.y = fmaf(q1.y, bf_hi(kw.z), acc.y);
        acc.z = fmaf(q1.z, bf_lo(kw.w), acc.z);
        acc.w = fmaf(q1.w, bf_hi(kw.w), acc.w);
        float pdot = (acc.x + acc.y) + (acc.z + acc.w);
        float4 pv = pl[(hp<<2) + s];
        float d0 = pc.x - pv.x, d1 = pc.y - pv.y;
        float d2 = pc.z - pv.z, d3 = pc.w - pv.w;
        float pdsq = fmaf(d0,d0, fmaf(d1,d1, fmaf(d2,d2, d3*d3)));
        return fmaf(pdot, scale, gcoef*pdsq);
    };

    float lp[13];
    float mx = -1e30f;

#define HPOS(KK) ((qy + (KK)/WIN_)*HALO_ + qx + ((KK)%WIN_))
#define LGROUP(G) { \
    float pr0 = partial(HPOS(4*(G)  )); \
    float pr1 = partial(HPOS(4*(G)+1)); \
    float pr2 = partial(HPOS(4*(G)+2)); \
    float pr3 = partial(HPOS(4*(G)+3)); \
    float Av = (c1 ? pr1 : pr0) + __shfl_xor(c1 ? pr0 : pr1, 1); \
    float Bv = (c1 ? pr3 : pr2) + __shfl_xor(c1 ? pr2 : pr3, 1); \
    float lg = (c2 ? Bv : Av) + __shfl_xor(c2 ? Av : Bv, 2); \
    lp[(G)] = lg; mx = fmaxf(mx, lg); }

    LGROUP(0) LGROUP(1) LGROUP(2) LGROUP(3) LGROUP(4) LGROUP(5)
    LGROUP(6) LGROUP(7) LGROUP(8) LGROUP(9) LGROUP(10) LGROUP(11)
    {   // kk = 48: all lanes hold it; only lane s==0 "owns" it
        float pr = partial(HPOS(48));
        pr += __shfl_xor(pr, 1);
        pr += __shfl_xor(pr, 2);
        lp[12] = pr; mx = fmaxf(mx, pr);
    }
    mx = fmaxf(mx, __shfl_xor(mx, 1));
    mx = fmaxf(mx, __shfl_xor(mx, 2));

    float ssum = 0.f;
#define EXPG(G) { float e = __expf(lp[(G)] - mx); lp[(G)] = e; ssum += e; }
    EXPG(0) EXPG(1) EXPG(2) EXPG(3) EXPG(4) EXPG(5)
    EXPG(6) EXPG(7) EXPG(8) EXPG(9) EXPG(10) EXPG(11)
    {
        float e = (s == 0) ? __expf(lp[12] - mx) : 0.f;
        lp[12] = e; ssum += e;
    }
    ssum += __shfl_xor(ssum, 1);
    ssum += __shfl_xor(ssum, 2);
    float inv = 1.0f / ssum;

    float4 o0 = make_float4(0.f,0.f,0.f,0.f);
    float4 o1 = make_float4(0.f,0.f,0.f,0.f);
#define PVPOS(KK) { \
    float wgt = __shfl(lp[(KK)>>2], (KK)&3, 4); \
    uint4 vw = vl[(HPOS(KK)<<2) + s]; \
    o0.x = fmaf(wgt, bf_lo(vw.x), o0.x); \
    o0.y = fmaf(wgt, bf_hi(vw.x), o0.y); \
    o0.z = fmaf(wgt, bf_lo(vw.y), o0.z); \
    o0.w = fmaf(wgt, bf_hi(vw.y), o0.w); \
    o1.x = fmaf(wgt, bf_lo(vw.z), o1.x); \
    o1.y = fmaf(wgt, bf_hi(vw.z), o1.y); \
    o1.z = fmaf(wgt, bf_lo(vw.w), o1.z); \
    o1.w = fmaf(wgt, bf_hi(vw.w), o1.w); }

    PVPOS(0)  PVPOS(1)  PVPOS(2)  PVPOS(3)  PVPOS(4)  PVPOS(5)  PVPOS(6)
    PVPOS(7)  PVPOS(8)  PVPOS(9)  PVPOS(10) PVPOS(11) PVPOS(12) PVPOS(13)
    PVPOS(14) PVPOS(15) PVPOS(16) PVPOS(17) PVPOS(18) PVPOS(19) PVPOS(20)
    PVPOS(21) PVPOS(22) PVPOS(23) PVPOS(24) PVPOS(25) PVPOS(26) PVPOS(27)
    PVPOS(28) PVPOS(29) PVPOS(30) PVPOS(31) PVPOS(32) PVPOS(33) PVPOS(34)
    PVPOS(35) PVPOS(36) PVPOS(37) PVPOS(38) PVPOS(39) PVPOS(40) PVPOS(41)
    PVPOS(42) PVPOS(43) PVPOS(44) PVPOS(45) PVPOS(46) PVPOS(47) PVPOS(48)

    float* aop = AO + ((size_t)b*N_ + n)*C_ + h*HD_ + s*8;
    o0.x *= inv; o0.y *= inv; o0.z *= inv; o0.w *= inv;
    o1.x *= inv; o1.y *= inv; o1.z *= inv; o1.w *= inv;
    ((float4*)aop)[0] = o0;
    ((float4*)aop)[1] = o1;
}

// ---------------------------------------------------------------------------
// Kernel 4: output projection, restructured like qkv_proj.
// 32 pixels/block (576 blocks); Wo staged in LDS halves (32 KB); AO tile
// transposed into LDS [ci][pix] via register staging (coalesced-enough float4
// loads + scalar ds_writes, 2 lanes/bank = free). Inner loop is pure LDS.
// ---------------------------------------------------------------------------
__global__ __launch_bounds__(256, 3) void out_proj(
    const float* __restrict__ AO, const float* __restrict__ Wo,
    const float* __restrict__ bo, float* __restrict__ out)
{
    __shared__ float4 ldsW4[64*32];   // 64 ci x 128 co (32 KB)
    __shared__ float  ldsX[128*32];   // [ci][pix] (16 KB)

    const int t  = threadIdx.x;
    const int b  = blockIdx.x / (N_/32);
    const int n0 = (blockIdx.x % (N_/32)) * 32;

    // stage AO tile transposed: thread loads float4 (4 ci) at one pixel,
    // scatters 4 scalars into [ci][pix]. banks: pix%32 distinct per 32 lanes.
    for (int idx = t; idx < 32*32; idx += 256) {
        int pix = idx & 31, c4 = idx >> 5;
        float4 v = ((const float4*)(AO + ((size_t)b*N_ + n0 + pix)*C_))[c4];
        ldsX[(c4*4+0)*32 + pix] = v.x;
        ldsX[(c4*4+1)*32 + pix] = v.y;
        ldsX[(c4*4+2)*32 + pix] = v.z;
        ldsX[(c4*4+3)*32 + pix] = v.w;
    }

    const int co_g  = t & 31;   // co = co_g*4 .. +3
    const int pix_g = t >> 5;   // pix = pix_g*4 .. +3

    float4 bias = *(const float4*)(bo + co_g*4);
    float4 acc0 = bias, acc1 = bias, acc2 = bias, acc3 = bias;
    for (int half = 0; half < 2; ++half) {
        __syncthreads();   // guards AO-stage (half 0) and ldsW readers (half 1)
        const float4* wsrc4 = (const float4*)(Wo + (size_t)half*64*C_);
        for (int idx = t; idx < 64*32; idx += 256) ldsW4[idx] = wsrc4[idx];
        __syncthreads();
        #pragma unroll 8
        for (int ci = 0; ci < 64; ++ci) {
            float4 xv = *(const float4*)(ldsX + (half*64 + ci)*32 + pix_g*4);
            float4 wv = ldsW4[ci*32 + co_g];
            fma4(acc0, xv.x, wv);
            fma4(acc1, xv.y, wv);
            fma4(acc2, xv.z, wv);
            fma4(acc3, xv.w, wv);
        }
    }
    // store: out[b][co][n], 16 scalars; block collectively fills whole lines.
    float4 accs[4] = {acc0, acc1, acc2, acc3};
    #pragma unroll
    for (int p = 0; p < 4; ++p) {
        int n = n0 + pix_g*4 + p;
        size_t base = ((size_t)b*C_ + co_g*4)*N_ + n;
        out[base        ] = accs[p].x;
        out[base +   N_ ] = accs[p].y;
        out[base + 2*N_ ] = accs[p].z;
        out[base + 3*N_ ] = accs[p].w;
    }
}

// ---------------------------------------------------------------------------
extern "C" void kernel_launch(void* const* d_in, const int* in_sizes, int n_in,
                              void* d_out, int out_size, void* d_ws, size_t ws_size,
                              hipStream_t stream)
{
    const float* x    = (const float*)d_in[0];
    const float* phi  = (const float*)d_in[1];
    const float* Wq   = (const float*)d_in[2];
    const float* bq   = (const float*)d_in[3];
    const float* Wk   = (const float*)d_in[4];
    const float* bk   = (const float*)d_in[5];
    const float* Wv   = (const float*)d_in[6];
    const float* bv   = (const float*)d_in[7];
    const float* Wo   = (const float*)d_in[8];
    const float* bo   = (const float*)d_in[9];
    const float* la   = (const float*)d_in[10];
    const float* beta = (const float*)d_in[11];
    float* out = (float*)d_out;

    // workspace layout. AO aliases Qp: each attn thread reads exactly the q
    // slice it later writes as AO (same n, same head, same channels).
    float* ws   = (float*)d_ws;
    float* Qp   = ws;                                        // 9.44 MB
    uint*  KVp  = (uint*)(Qp + (size_t)B_*N_*C_);            // 10.65 MB
    float* PhiT = (float*)(KVp + (size_t)B_*HEADS_*HP2_*32); // 1.33 MB
    float* AO   = Qp;                                        // aliased

    pad_fill<<<dim3((B_*HP2_ + 255)/256), dim3(256), 0, stream>>>(phi, bk, bv, KVp, PhiT);
    qkv_proj<<<dim3(N_/32, B_, 3), dim3(256), 0, stream>>>(x, Wq, bq, Wk, bk, Wv, bv, Qp, KVp);
    attn<<<dim3((H_/TILE_)*(W_/TILE_), HEADS_, B_), dim3(256), 0, stream>>>(Qp, KVp, PhiT, la, beta, AO);
    out_proj<<<dim3(B_*(N_/32)), dim3(256), 0, stream>>>(AO, Wo, bo, out);
}

// Round 7
// 93.586 us; speedup vs baseline: 2.3593x; 1.0250x over previous
//
#include <hip/hip_runtime.h>

typedef unsigned int uint;

#define B_ 2
#define C_ 128
#define H_ 96
#define W_ 96
#define HEADS_ 4
#define HD_ 32
#define M_ 16
#define WIN_ 7
#define PAD_ 3
#define N_ (H_*W_)              // 9216
#define HP_ (H_+2*PAD_)         // 102
#define HP2_ (HP_*HP_)          // 10404
#define KW_ (WIN_*WIN_)         // 49
#define TILE_ 8                 // attn tile is 8x8 pixels
#define HALO_ (TILE_+WIN_-1)    // 14
#define NHALO_ (HALO_*HALO_)    // 196

static __device__ __forceinline__ uint f2bf(float f) {
    uint u = __float_as_uint(f);
    u = (u + 0x7fffu + ((u >> 16) & 1u)) >> 16;   // RNE to bf16
    return u & 0xffffu;
}
static __device__ __forceinline__ uint pack2(float a, float b) {
    return f2bf(a) | (f2bf(b) << 16);
}
static __device__ __forceinline__ float bf_lo(uint u){ return __uint_as_float(u << 16); }
static __device__ __forceinline__ float bf_hi(uint u){ return __uint_as_float(u & 0xffff0000u); }

// inline function, not a macro: macro params named w/x/y/z collide with
// float4 member access under preprocessor substitution.
static __device__ __forceinline__ void fma4(float4& acc, float s, const float4& v) {
    acc.x = fmaf(s, v.x, acc.x);
    acc.y = fmaf(s, v.y, acc.y);
    acc.z = fmaf(s, v.z, acc.z);
    acc.w = fmaf(s, v.w, acc.w);
}

// Intra-quad cross-lane via DPP quad_perm (VALU pipe, 2cyc) instead of
// __shfl_* (ds_swizzle/ds_bpermute: LDS pipe + lgkmcnt latency).
// quad_perm ctrl = sel3<<6 | sel2<<4 | sel1<<2 | sel0.
template<int CTRL>
static __device__ __forceinline__ float dpp_mov(float v) {
    return __int_as_float(__builtin_amdgcn_update_dpp(
        0, __float_as_int(v), CTRL, 0xF, 0xF, false));
}
#define DPP_XOR1(v)  dpp_mov<0xB1>(v)   // [1,0,3,2]
#define DPP_XOR2(v)  dpp_mov<0x4E>(v)   // [2,3,0,1]
#define DPP_BCAST0(v) dpp_mov<0x00>(v)
#define DPP_BCAST1(v) dpp_mov<0x55>(v)
#define DPP_BCAST2(v) dpp_mov<0xAA>(v)
#define DPP_BCAST3(v) dpp_mov<0xFF>(v)

// ---------------------------------------------------------------------------
// KVp layout (head-major, K/V interleaved, bf16 pairs):
//   KVp[((b*HEADS+h)*HP2 + row)*32 + u], u<16: K pair u, u>=16: V pair u-16.
// One (row, head) = 128B = exactly one cache line; attn consumes lines fully.
// ---------------------------------------------------------------------------

// Kernel 1: fill padded borders of KVp with bias (= proj of zero input), and
// build PhiT: [B][102][102][16] fp32, border = 1.0
__global__ __launch_bounds__(256) void pad_fill(
    const float* __restrict__ phi, const float* __restrict__ bk, const float* __restrict__ bv,
    uint* __restrict__ KVp, float* __restrict__ PhiT)
{
    int idx = blockIdx.x * 256 + threadIdx.x;
    if (idx >= B_*HP2_) return;
    int b  = idx / HP2_;
    int pp = idx % HP2_;
    int py = pp / HP_, px = pp % HP_;
    bool interior = (py >= PAD_ && py < H_+PAD_ && px >= PAD_ && px < W_+PAD_);
    if (!interior) {
        #pragma unroll
        for (int h = 0; h < HEADS_; ++h) {
            size_t base = ((size_t)(b*HEADS_+h)*HP2_ + pp) * 32;
            #pragma unroll
            for (int q4i = 0; q4i < 4; ++q4i) {
                const float* kb8 = bk + h*HD_ + q4i*8;
                const float* vb8 = bv + h*HD_ + q4i*8;
                uint4 ku, vu;
                ku.x = pack2(kb8[0],kb8[1]); ku.y = pack2(kb8[2],kb8[3]);
                ku.z = pack2(kb8[4],kb8[5]); ku.w = pack2(kb8[6],kb8[7]);
                vu.x = pack2(vb8[0],vb8[1]); vu.y = pack2(vb8[2],vb8[3]);
                vu.z = pack2(vb8[4],vb8[5]); vu.w = pack2(vb8[6],vb8[7]);
                ((uint4*)(KVp + base))[q4i]     = ku;
                ((uint4*)(KVp + base))[4 + q4i] = vu;
            }
        }
    }
    size_t pb = ((size_t)b*HP2_ + pp) * M_;
    if (interior) {
        int y = py - PAD_, xx = px - PAD_;
        #pragma unroll
        for (int m = 0; m < M_; ++m)
            PhiT[pb + m] = phi[((size_t)b*M_ + m)*N_ + y*W_ + xx];
    } else {
        #pragma unroll
        for (int m = 0; m < M_; ++m) PhiT[pb + m] = 1.0f;
    }
}

// ---------------------------------------------------------------------------
// Kernel 2: Q/K/V projection, one projection per block (grid.z = 0/1/2).
// 32 pixels/block; x tile (16KB) + W half (32KB) in LDS; 4co x 4pix per thread.
// ---------------------------------------------------------------------------
__global__ __launch_bounds__(256, 3) void qkv_proj(
    const float* __restrict__ x,
    const float* __restrict__ Wq, const float* __restrict__ bq,
    const float* __restrict__ Wk, const float* __restrict__ bk,
    const float* __restrict__ Wv, const float* __restrict__ bv,
    float* __restrict__ Qp, uint* __restrict__ KVp)
{
    __shared__ float4 ldsW4[64*32];   // 64 ci x 128 co (32 KB)
    __shared__ float4 ldsX4[128*8];   // [ci][pix] 128 x 32 (16 KB)

    const int t  = threadIdx.x;
    const int n0 = blockIdx.x * 32;
    const int b  = blockIdx.y;
    const int pj = blockIdx.z;
    const float* Wsrc = (pj == 0) ? Wq : (pj == 1) ? Wk : Wv;
    const float* bsrc = (pj == 0) ? bq : (pj == 1) ? bk : bv;

    for (int idx = t; idx < 128*32; idx += 256) {
        int pix = idx & 31, ci = idx >> 5;
        ((float*)ldsX4)[ci*32 + pix] = x[((size_t)b*C_ + ci)*N_ + n0 + pix];
    }

    const int co_g  = t & 31;   // co = co_g*4 .. +3
    const int pix_g = t >> 5;   // pix = pix_g*4 .. +3

    float4 bias = *(const float4*)(bsrc + co_g*4);
    float4 acc0 = bias, acc1 = bias, acc2 = bias, acc3 = bias;
    for (int half = 0; half < 2; ++half) {
        __syncthreads();   // guards x-stage (half 0) and ldsW readers (half 1)
        const float4* wsrc4 = (const float4*)(Wsrc + (size_t)half*64*C_);
        for (int idx = t; idx < 64*32; idx += 256) ldsW4[idx] = wsrc4[idx];
        __syncthreads();
        #pragma unroll 8
        for (int ci = 0; ci < 64; ++ci) {
            float4 xv = ldsX4[(half*64 + ci)*8 + pix_g];
            float4 wv = ldsW4[ci*32 + co_g];
            fma4(acc0, xv.x, wv);
            fma4(acc1, xv.y, wv);
            fma4(acc2, xv.z, wv);
            fma4(acc3, xv.w, wv);
        }
    }
    float4 accs[4] = {acc0, acc1, acc2, acc3};
    #pragma unroll
    for (int p = 0; p < 4; ++p) {
        int n = n0 + pix_g*4 + p;
        if (pj == 0) {
            *(float4*)(Qp + ((size_t)b*N_ + n)*C_ + co_g*4) = accs[p];
        } else {
            int y = n / W_, xx = n % W_;
            size_t rowb = (size_t)(y+PAD_)*HP_ + (xx+PAD_);
            int h = co_g >> 3;
            int u = ((pj == 1) ? 0 : 16) + (co_g & 7)*2;
            uint2 uu;
            uu.x = pack2(accs[p].x, accs[p].y);
            uu.y = pack2(accs[p].z, accs[p].w);
            *(uint2*)(KVp + ((size_t)(b*HEADS_+h)*HP2_ + rowb)*32 + u) = uu;
        }
    }
}

// ---------------------------------------------------------------------------
// Kernel 3: local attention, 4 threads per (pixel, head), fully macro-unrolled
// (lp[] literal-indexed only -> registers); ALL cross-lane ops are intra-quad
// DPP quad_perm moves on the VALU pipe.
// ---------------------------------------------------------------------------
__global__ __launch_bounds__(256, 3) void attn(
    const float* __restrict__ Qp, const uint* __restrict__ KVp,
    const float* __restrict__ PhiT, const float* __restrict__ log_alpha,
    const float* __restrict__ beta, float* __restrict__ AO)
{
    __shared__ uint4  kl[NHALO_*4];   // 12544 B
    __shared__ uint4  vl[NHALO_*4];   // 12544 B
    __shared__ float4 pl[NHALO_*4];   // 12544 B

    const int t  = threadIdx.x;
    const int h  = blockIdx.y;
    const int b  = blockIdx.z;
    const int bx = blockIdx.x;
    const int tile = ((bx & 7) * 18) + (bx >> 3);   // 144 = 8*18, bijective
    const int y0 = (tile / (W_/TILE_)) * TILE_;
    const int x0 = (tile % (W_/TILE_)) * TILE_;

    // stage K/V halo: one full 128B line per (row, head)
    const uint* kvb = KVp + (size_t)(b*HEADS_+h)*HP2_*32;
    for (int idx = t; idx < NHALO_*8; idx += 256) {
        int hp = idx >> 3, u4 = idx & 7;
        int hy = hp / HALO_, hx = hp % HALO_;
        size_t rowb = (size_t)(y0+hy)*HP_ + (x0+hx);
        uint4 val = *(const uint4*)(kvb + rowb*32 + u4*4);
        if (u4 < 4) kl[hp*4 + u4] = val;
        else        vl[hp*4 + (u4-4)] = val;
    }
    // stage phi halo (fp32)
    const float* pbase = PhiT + (size_t)b*HP2_*M_;
    for (int idx = t; idx < NHALO_*4; idx += 256) {
        int hp = idx >> 2, sb = idx & 3;
        int hy = hp / HALO_, hx = hp % HALO_;
        size_t rowb = (size_t)(y0+hy)*HP_ + (x0+hx);
        pl[idx] = *(const float4*)(pbase + rowb*M_ + sb*4);
    }
    __syncthreads();

    const int s  = t & 3;       // sub-lane: channels s*8.., phi dims s*4..
    const int p  = t >> 2;      // pixel 0..63
    const int qy = p >> 3, qx = p & 7;
    const int n  = (y0+qy)*W_ + (x0+qx);
    const bool c1 = (s & 1) != 0;
    const bool c2 = (s & 2) != 0;

    float4 q0, q1;
    {
        const float* qptr = Qp + ((size_t)b*N_ + n)*C_ + h*HD_ + s*8;
        q0 = ((const float4*)qptr)[0];
        q1 = ((const float4*)qptr)[1];
    }
    float4 pc = pl[((qy+PAD_)*HALO_ + (qx+PAD_))*4 + s];

    const float alpha = __expf(log_alpha[0]);
    const float scale = 0.17677669529663687f;                 // HD^-0.5
    const float gcoef = -beta[h] * alpha * 0.17677669529663687f; // -beta*alpha/sqrt(2M)

    auto partial = [&](int hp) -> float {
        uint4 kw = kl[(hp<<2) + s];
        float4 acc = make_float4(0.f,0.f,0.f,0.f);
        acc.x = fmaf(q0.x, bf_lo(kw.x), acc.x);
        acc.y = fmaf(q0.y, bf_hi(kw.x), acc.y);
        acc.z = fmaf(q0.z, bf_lo(kw.y), acc.z);
        acc.w = fmaf(q0.w, bf_hi(kw.y), acc.w);
        acc.x = fmaf(q1.x, bf_lo(kw.z), acc.x);
        acc.y = fmaf(q1.y, bf_hi(kw.z), acc.y);
        acc.z = fmaf(q1.z, bf_lo(kw.w), acc.z);
        acc.w = fmaf(q1.w, bf_hi(kw.w), acc.w);
        float pdot = (acc.x + acc.y) + (acc.z + acc.w);
        float4 pv = pl[(hp<<2) + s];
        float d0 = pc.x - pv.x, d1 = pc.y - pv.y;
        float d2 = pc.z - pv.z, d3 = pc.w - pv.w;
        float pdsq = fmaf(d0,d0, fmaf(d1,d1, fmaf(d2,d2, d3*d3)));
        return fmaf(pdot, scale, gcoef*pdsq);
    };

    float lp[13];
    float mx = -1e30f;

#define HPOS(KK) ((qy + (KK)/WIN_)*HALO_ + qx + ((KK)%WIN_))
#define LGROUP(G) { \
    float pr0 = partial(HPOS(4*(G)  )); \
    float pr1 = partial(HPOS(4*(G)+1)); \
    float pr2 = partial(HPOS(4*(G)+2)); \
    float pr3 = partial(HPOS(4*(G)+3)); \
    float Av = (c1 ? pr1 : pr0) + DPP_XOR1(c1 ? pr0 : pr1); \
    float Bv = (c1 ? pr3 : pr2) + DPP_XOR1(c1 ? pr2 : pr3); \
    float lg = (c2 ? Bv : Av) + DPP_XOR2(c2 ? Av : Bv); \
    lp[(G)] = lg; mx = fmaxf(mx, lg); }

    LGROUP(0) LGROUP(1) LGROUP(2) LGROUP(3) LGROUP(4) LGROUP(5)
    LGROUP(6) LGROUP(7) LGROUP(8) LGROUP(9) LGROUP(10) LGROUP(11)
    {   // kk = 48: all lanes hold it; only lane s==0 "owns" it
        float pr = partial(HPOS(48));
        pr += DPP_XOR1(pr);
        pr += DPP_XOR2(pr);
        lp[12] = pr; mx = fmaxf(mx, pr);
    }
    mx = fmaxf(mx, DPP_XOR1(mx));
    mx = fmaxf(mx, DPP_XOR2(mx));

    float ssum = 0.f;
#define EXPG(G) { float e = __expf(lp[(G)] - mx); lp[(G)] = e; ssum += e; }
    EXPG(0) EXPG(1) EXPG(2) EXPG(3) EXPG(4) EXPG(5)
    EXPG(6) EXPG(7) EXPG(8) EXPG(9) EXPG(10) EXPG(11)
    {
        float e = (s == 0) ? __expf(lp[12] - mx) : 0.f;
        lp[12] = e; ssum += e;
    }
    ssum += DPP_XOR1(ssum);
    ssum += DPP_XOR2(ssum);
    float inv = 1.0f / ssum;

    float4 o0 = make_float4(0.f,0.f,0.f,0.f);
    float4 o1 = make_float4(0.f,0.f,0.f,0.f);
#define PVPOS(KK, BC) { \
    float wgt = DPP_BCAST##BC(lp[(KK)>>2]); \
    uint4 vw = vl[(HPOS(KK)<<2) + s]; \
    o0.x = fmaf(wgt, bf_lo(vw.x), o0.x); \
    o0.y = fmaf(wgt, bf_hi(vw.x), o0.y); \
    o0.z = fmaf(wgt, bf_lo(vw.y), o0.z); \
    o0.w = fmaf(wgt, bf_hi(vw.y), o0.w); \
    o1.x = fmaf(wgt, bf_lo(vw.z), o1.x); \
    o1.y = fmaf(wgt, bf_hi(vw.z), o1.y); \
    o1.z = fmaf(wgt, bf_lo(vw.w), o1.z); \
    o1.w = fmaf(wgt, bf_hi(vw.w), o1.w); }

    PVPOS(0,0)  PVPOS(1,1)  PVPOS(2,2)  PVPOS(3,3)  PVPOS(4,0)  PVPOS(5,1)  PVPOS(6,2)
    PVPOS(7,3)  PVPOS(8,0)  PVPOS(9,1)  PVPOS(10,2) PVPOS(11,3) PVPOS(12,0) PVPOS(13,1)
    PVPOS(14,2) PVPOS(15,3) PVPOS(16,0) PVPOS(17,1) PVPOS(18,2) PVPOS(19,3) PVPOS(20,0)
    PVPOS(21,1) PVPOS(22,2) PVPOS(23,3) PVPOS(24,0) PVPOS(25,1) PVPOS(26,2) PVPOS(27,3)
    PVPOS(28,0) PVPOS(29,1) PVPOS(30,2) PVPOS(31,3) PVPOS(32,0) PVPOS(33,1) PVPOS(34,2)
    PVPOS(35,3) PVPOS(36,0) PVPOS(37,1) PVPOS(38,2) PVPOS(39,3) PVPOS(40,0) PVPOS(41,1)
    PVPOS(42,2) PVPOS(43,3) PVPOS(44,0) PVPOS(45,1) PVPOS(46,2) PVPOS(47,3) PVPOS(48,0)

    float* aop = AO + ((size_t)b*N_ + n)*C_ + h*HD_ + s*8;
    o0.x *= inv; o0.y *= inv; o0.z *= inv; o0.w *= inv;
    o1.x *= inv; o1.y *= inv; o1.z *= inv; o1.w *= inv;
    ((float4*)aop)[0] = o0;
    ((float4*)aop)[1] = o1;
}

// ---------------------------------------------------------------------------
// Kernel 4: output projection, restructured like qkv_proj.
// 32 pixels/block (576 blocks); Wo staged in LDS halves (32 KB); AO tile
// transposed into LDS [ci][pix] via register staging. Inner loop pure LDS.
// ---------------------------------------------------------------------------
__global__ __launch_bounds__(256, 3) void out_proj(
    const float* __restrict__ AO, const float* __restrict__ Wo,
    const float* __restrict__ bo, float* __restrict__ out)
{
    __shared__ float4 ldsW4[64*32];   // 64 ci x 128 co (32 KB)
    __shared__ float  ldsX[128*32];   // [ci][pix] (16 KB)

    const int t  = threadIdx.x;
    const int b  = blockIdx.x / (N_/32);
    const int n0 = (blockIdx.x % (N_/32)) * 32;

    for (int idx = t; idx < 32*32; idx += 256) {
        int pix = idx & 31, c4 = idx >> 5;
        float4 v = ((const float4*)(AO + ((size_t)b*N_ + n0 + pix)*C_))[c4];
        ldsX[(c4*4+0)*32 + pix] = v.x;
        ldsX[(c4*4+1)*32 + pix] = v.y;
        ldsX[(c4*4+2)*32 + pix] = v.z;
        ldsX[(c4*4+3)*32 + pix] = v.w;
    }

    const int co_g  = t & 31;   // co = co_g*4 .. +3
    const int pix_g = t >> 5;   // pix = pix_g*4 .. +3

    float4 bias = *(const float4*)(bo + co_g*4);
    float4 acc0 = bias, acc1 = bias, acc2 = bias, acc3 = bias;
    for (int half = 0; half < 2; ++half) {
        __syncthreads();   // guards AO-stage (half 0) and ldsW readers (half 1)
        const float4* wsrc4 = (const float4*)(Wo + (size_t)half*64*C_);
        for (int idx = t; idx < 64*32; idx += 256) ldsW4[idx] = wsrc4[idx];
        __syncthreads();
        #pragma unroll 8
        for (int ci = 0; ci < 64; ++ci) {
            float4 xv = *(const float4*)(ldsX + (half*64 + ci)*32 + pix_g*4);
            float4 wv = ldsW4[ci*32 + co_g];
            fma4(acc0, xv.x, wv);
            fma4(acc1, xv.y, wv);
            fma4(acc2, xv.z, wv);
            fma4(acc3, xv.w, wv);
        }
    }
    float4 accs[4] = {acc0, acc1, acc2, acc3};
    #pragma unroll
    for (int p = 0; p < 4; ++p) {
        int n = n0 + pix_g*4 + p;
        size_t base = ((size_t)b*C_ + co_g*4)*N_ + n;
        out[base        ] = accs[p].x;
        out[base +   N_ ] = accs[p].y;
        out[base + 2*N_ ] = accs[p].z;
        out[base + 3*N_ ] = accs[p].w;
    }
}

// ---------------------------------------------------------------------------
extern "C" void kernel_launch(void* const* d_in, const int* in_sizes, int n_in,
                              void* d_out, int out_size, void* d_ws, size_t ws_size,
                              hipStream_t stream)
{
    const float* x    = (const float*)d_in[0];
    const float* phi  = (const float*)d_in[1];
    const float* Wq   = (const float*)d_in[2];
    const float* bq   = (const float*)d_in[3];
    const float* Wk   = (const float*)d_in[4];
    const float* bk   = (const float*)d_in[5];
    const float* Wv   = (const float*)d_in[6];
    const float* bv   = (const float*)d_in[7];
    const float* Wo   = (const float*)d_in[8];
    const float* bo   = (const float*)d_in[9];
    const float* la   = (const float*)d_in[10];
    const float* beta = (const float*)d_in[11];
    float* out = (float*)d_out;

    // workspace layout. AO aliases Qp: each attn thread reads exactly the q
    // slice it later writes as AO (same n, same head, same channels).
    float* ws   = (float*)d_ws;
    float* Qp   = ws;                                        // 9.44 MB
    uint*  KVp  = (uint*)(Qp + (size_t)B_*N_*C_);            // 10.65 MB
    float* PhiT = (float*)(KVp + (size_t)B_*HEADS_*HP2_*32); // 1.33 MB
    float* AO   = Qp;                                        // aliased

    pad_fill<<<dim3((B_*HP2_ + 255)/256), dim3(256), 0, stream>>>(phi, bk, bv, KVp, PhiT);
    qkv_proj<<<dim3(N_/32, B_, 3), dim3(256), 0, stream>>>(x, Wq, bq, Wk, bk, Wv, bv, Qp, KVp);
    attn<<<dim3((H_/TILE_)*(W_/TILE_), HEADS_, B_), dim3(256), 0, stream>>>(Qp, KVp, PhiT, la, beta, AO);
    out_proj<<<dim3(B_*(N_/32)), dim3(256), 0, stream>>>(AO, Wo, bo, out);
}